// Round 1
// baseline (737.204 us; speedup 1.0000x reference)
//
#include <hip/hip_runtime.h>
#include <math.h>

// Problem constants
#define H 128
#define Wd 128
#define KH 16
#define KW 16
#define SH 113          // H-KH+1
#define SW 113          // Wd-KW+1
#define XC 32           // x-positions per thread-task
#define NSLOT 452       // 4 x-tiles * 113 rows

// ---------------- prep: wn = w / sqrt(sum(w^2)/n), n = 16384 ----------------
__global__ __launch_bounds__(256) void prep_wn(const float* __restrict__ w,
                                               float* __restrict__ wn) {
    __shared__ float red[256];
    int t = threadIdx.x;
    float wv = w[t];
    red[t] = wv * wv;
    __syncthreads();
    for (int off = 128; off > 0; off >>= 1) {
        if (t < off) red[t] += red[t + off];
        __syncthreads();
    }
    float denom = sqrtf(red[0] / 16384.0f);
    wn[t] = wv / denom;
}

// ---------------- main: scores -> argmax|.| -> scatter smax*wn ----------------
// One block per sample. 64KB LDS tile with per-row chunk rotation swizzle:
// row y, float4-chunk c stored at chunk' = (c+y)&31  -> bank 4(c+y)%32,
// y-major lane mapping => 2-way (free) on ds_read_b128 / ds_write_b128.
__global__ __launch_bounds__(256, 2) void gtpca_main(
    const float* __restrict__ in, const float* __restrict__ wn,
    float* __restrict__ out) {
    __shared__ float4 tile4[4096];           // exactly 64 KB
    float* tile = (float*)tile4;

    const int tid = threadIdx.x;
    const int b = blockIdx.x;
    const float4* in4 = (const float4*)(in + (size_t)b * (H * Wd));

    // ---- load sample into LDS (swizzled) ----
#pragma unroll
    for (int i = 0; i < 16; ++i) {
        int g = tid + i * 256;               // float4 index 0..4095
        int y = g >> 5;                      // row
        int c = g & 31;                      // chunk in row
        tile4[(y << 5) | ((c + y) & 31)] = in4[g];
    }
    __syncthreads();

    // ---- compute scores, per-thread argmax of |score| (first occurrence) ----
    float best_a = -1.0f;
    int best_i = 0x7FFFFFFF;
    float best_v = 0.0f;

#pragma unroll 1
    for (int it = 0; it < 2; ++it) {
        int s = it * 256 + tid;
        if (s < NSLOT) {
            int y = s % 113;                 // score row
            int xt = s / 113;                // x-tile (0..3)
            int cbase = xt << 3;             // chunk base = (32*xt)/4
            float acc[XC];
#pragma unroll
            for (int i = 0; i < XC; ++i) acc[i] = 0.0f;

#pragma unroll 1
            for (int ki = 0; ki < KH; ++ki) {
                int r = y + ki;              // input row (<=127)
                int rc = cbase + r;          // rotation pre-add
                const float4* rowp = tile4 + (r << 5);
                float seg[XC + 16];
#pragma unroll
                for (int q = 0; q < 12; ++q) {
                    float4 v = rowp[(rc + q) & 31];
                    seg[4 * q + 0] = v.x;
                    seg[4 * q + 1] = v.y;
                    seg[4 * q + 2] = v.z;
                    seg[4 * q + 3] = v.w;
                }
                const float* wrow = wn + ki * 16;  // wave-uniform -> s_load
#pragma unroll
                for (int kj = 0; kj < KW; ++kj) {
                    float wv = wrow[kj];
#pragma unroll
                    for (int xc = 0; xc < XC; ++xc)
                        acc[xc] += seg[xc + kj] * wv;
                }
            }

            int xbase = xt << 5;
#pragma unroll
            for (int xc = 0; xc < XC; ++xc) {
                int p = xbase + xc;
                if (p < SW) {
                    float a = fabsf(acc[xc]);
                    int idx = y * SW + p;
                    if (a > best_a || (a == best_a && idx < best_i)) {
                        best_a = a;
                        best_i = idx;
                        best_v = acc[xc];
                    }
                }
            }
        }
    }

    // ---- block reduction (alias tile; everyone is done reading it) ----
    __syncthreads();
    float* red_a = tile;                      // [256]
    int* red_i = (int*)(tile + 256);          // [256]
    float* red_v = tile + 512;                // [256]
    red_a[tid] = best_a;
    red_i[tid] = best_i;
    red_v[tid] = best_v;
    __syncthreads();
    for (int off = 128; off > 0; off >>= 1) {
        if (tid < off) {
            float a2 = red_a[tid + off];
            int i2 = red_i[tid + off];
            float v2 = red_v[tid + off];
            if (a2 > red_a[tid] || (a2 == red_a[tid] && i2 < red_i[tid])) {
                red_a[tid] = a2;
                red_i[tid] = i2;
                red_v[tid] = v2;
            }
        }
        __syncthreads();
    }
    int bi = red_i[0];
    float sv = red_v[0] * (1.0f / 16384.0f);  // exact: /2^14
    int rr = bi / SW;
    int cc = bi % SW;

    // ---- output: zeros + smax*wn block at (rr,cc) ----
    float4* out4 = (float4*)(out + (size_t)b * (H * Wd));
#pragma unroll
    for (int i = 0; i < 16; ++i) {
        int g = tid + i * 256;
        int orow = g >> 5;
        int ocol = (g & 31) << 2;
        float4 v = {0.0f, 0.0f, 0.0f, 0.0f};
        int dr = orow - rr;
        if ((unsigned)dr < 16u) {
            float* vp = (float*)&v;
#pragma unroll
            for (int k = 0; k < 4; ++k) {
                int dc = ocol + k - cc;
                if ((unsigned)dc < 16u) vp[k] = sv * wn[dr * 16 + dc];
            }
        }
        out4[g] = v;
    }
}

extern "C" void kernel_launch(void* const* d_in, const int* in_sizes, int n_in,
                              void* d_out, int out_size, void* d_ws, size_t ws_size,
                              hipStream_t stream) {
    const float* in = (const float*)d_in[0];   // (4096,128,128) fp32
    const float* w = (const float*)d_in[1];    // (16,16) fp32
    float* out = (float*)d_out;                // (4096,128,128) fp32
    float* wn = (float*)d_ws;                  // 256 floats scratch

    prep_wn<<<1, 256, 0, stream>>>(w, wn);
    gtpca_main<<<4096, 256, 0, stream>>>(in, wn, out);
}

// Round 2
// 725.966 us; speedup vs baseline: 1.0155x; 1.0155x over previous
//
#include <hip/hip_runtime.h>
#include <math.h>

// Problem constants
#define H 128
#define Wd 128
#define KH 16
#define KW 16
#define SW 113          // Wd-KW+1 (== SH)

// LDS swizzle: row r, float4-chunk c (0..31) stored at
//   phys = (c & 24) | ((c ^ ((r>>1)&7)) & 7)
// Compute lanes have consecutive (r>>1) across each 8-lane b128 phase ->
// all 8 bank-groups distinct -> conflict-free.
__device__ __forceinline__ int swz(int c, int r) {
    return (c & 24) | ((c ^ ((r >> 1) & 7)) & 7);
}

// ---------------- prep: wn = w / sqrt(sum(w^2)/n), n = 16384 ----------------
__global__ __launch_bounds__(256) void prep_wn(const float* __restrict__ w,
                                               float* __restrict__ wn) {
    __shared__ float red[256];
    int t = threadIdx.x;
    float wv = w[t];
    red[t] = wv * wv;
    __syncthreads();
    for (int off = 128; off > 0; off >>= 1) {
        if (t < off) red[t] += red[t + off];
        __syncthreads();
    }
    float denom = sqrtf(red[0] / 16384.0f);
    wn[t] = wv / denom;
}

// ---------------- main: scores -> argmax|.| -> scatter smax*wn ----------------
// One block (256 thr) per sample. Thread (p=lane, xt=wave-uniform) computes
// score rows y0=2p, y0+1 at x-positions 16*xt .. 16*xt+15. The 17 input rows
// y0..y0+16 are each read ONCE (8 ds_read_b128) and feed both score rows.
__global__ __launch_bounds__(256, 2) void gtpca_main(
    const float* __restrict__ in, const float* __restrict__ wn,
    float* __restrict__ out) {
    __shared__ float4 tile4[4096];           // exactly 64 KB
    float* tile = (float*)tile4;

    const int tid = threadIdx.x;
    const int b = blockIdx.x;
    const float4* in4 = (const float4*)(in + (size_t)b * (H * Wd));

    // ---- load sample into LDS (swizzled) ----
#pragma unroll
    for (int i = 0; i < 16; ++i) {
        int g = tid + i * 256;               // float4 index 0..4095
        int y = g >> 5;                      // row
        int c = g & 31;                      // chunk in row
        tile4[(y << 5) | swz(c, y)] = in4[g];
    }
    __syncthreads();

    float best_a = -1.0f;
    int best_i = 0x7FFFFFFF;
    float best_v = 0.0f;

#pragma unroll 1
    for (int it = 0; it < 2; ++it) {
        int s = it * 256 + tid;
        int p = s & 63;                      // lane = row-pair index
        int xt = s >> 6;                     // x-tile 0..7 (wave-uniform)
        if (p < 57) {
            const int y0 = p * 2;            // score rows y0, y0+1
            const int cbase = xt * 4;        // chunk base (wave-uniform)
            float acc0[16], acc1[16];
#pragma unroll
            for (int i = 0; i < 16; ++i) { acc0[i] = 0.0f; acc1[i] = 0.0f; }
            float seg[32];

            // ro = 0: feeds acc0 only (ki=0)
            {
                const int r = y0;
                const float4* rowp = tile4 + (r << 5);
#pragma unroll
                for (int q = 0; q < 8; ++q) {
                    float4 v = rowp[swz(cbase + q, r)];
                    seg[4*q+0] = v.x; seg[4*q+1] = v.y;
                    seg[4*q+2] = v.z; seg[4*q+3] = v.w;
                }
                const float* wr = wn;        // ki = 0
#pragma unroll
                for (int kj = 0; kj < 16; ++kj) {
                    float wv = wr[kj];
#pragma unroll
                    for (int x = 0; x < 16; ++x) acc0[x] += seg[x + kj] * wv;
                }
            }

            // ro = 1..15: feeds acc0 (ki=ro) and acc1 (ki=ro-1)
#pragma unroll 1
            for (int ro = 1; ro < 16; ++ro) {
                const int r = y0 + ro;
                const float4* rowp = tile4 + (r << 5);
#pragma unroll
                for (int q = 0; q < 8; ++q) {
                    float4 v = rowp[swz(cbase + q, r)];
                    seg[4*q+0] = v.x; seg[4*q+1] = v.y;
                    seg[4*q+2] = v.z; seg[4*q+3] = v.w;
                }
                const float* wr0 = wn + ro * 16;
                const float* wr1 = wn + (ro - 1) * 16;
#pragma unroll
                for (int kj = 0; kj < 16; ++kj) {
                    float wv0 = wr0[kj];
                    float wv1 = wr1[kj];
#pragma unroll
                    for (int x = 0; x < 16; ++x) acc0[x] += seg[x + kj] * wv0;
#pragma unroll
                    for (int x = 0; x < 16; ++x) acc1[x] += seg[x + kj] * wv1;
                }
            }

            // ro = 16: feeds acc1 only (ki=15). Clamp row for p=56 (r=128).
            {
                int r = y0 + 16; if (r > 127) r = 127;  // p=56: acc1 discarded
                const float4* rowp = tile4 + (r << 5);
#pragma unroll
                for (int q = 0; q < 8; ++q) {
                    float4 v = rowp[swz(cbase + q, r)];
                    seg[4*q+0] = v.x; seg[4*q+1] = v.y;
                    seg[4*q+2] = v.z; seg[4*q+3] = v.w;
                }
                const float* wr = wn + 15 * 16;
#pragma unroll
                for (int kj = 0; kj < 16; ++kj) {
                    float wv = wr[kj];
#pragma unroll
                    for (int x = 0; x < 16; ++x) acc1[x] += seg[x + kj] * wv;
                }
            }

            // ---- per-thread argmax candidates ----
            const int xb = xt * 16;
#pragma unroll
            for (int x = 0; x < 16; ++x) {
                int xpos = xb + x;
                if (xpos < SW) {
                    float a = fabsf(acc0[x]);
                    int idx = y0 * SW + xpos;
                    if (a > best_a || (a == best_a && idx < best_i)) {
                        best_a = a; best_i = idx; best_v = acc0[x];
                    }
                }
            }
            if (y0 + 1 < SW) {
#pragma unroll
                for (int x = 0; x < 16; ++x) {
                    int xpos = xb + x;
                    if (xpos < SW) {
                        float a = fabsf(acc1[x]);
                        int idx = (y0 + 1) * SW + xpos;
                        if (a > best_a || (a == best_a && idx < best_i)) {
                            best_a = a; best_i = idx; best_v = acc1[x];
                        }
                    }
                }
            }
        }
    }

    // ---- block reduction (alias tile; everyone is done reading it) ----
    __syncthreads();
    float* red_a = tile;                      // [256]
    int* red_i = (int*)(tile + 256);          // [256]
    float* red_v = tile + 512;                // [256]
    red_a[tid] = best_a;
    red_i[tid] = best_i;
    red_v[tid] = best_v;
    __syncthreads();
    for (int off = 128; off > 0; off >>= 1) {
        if (tid < off) {
            float a2 = red_a[tid + off];
            int i2 = red_i[tid + off];
            float v2 = red_v[tid + off];
            if (a2 > red_a[tid] || (a2 == red_a[tid] && i2 < red_i[tid])) {
                red_a[tid] = a2;
                red_i[tid] = i2;
                red_v[tid] = v2;
            }
        }
        __syncthreads();
    }
    int bi = red_i[0];
    float sv = red_v[0] * (1.0f / 16384.0f);  // exact: /2^14
    int rr = bi / SW;
    int cc = bi % SW;

    // ---- output: zeros + smax*wn block at (rr,cc) ----
    float4* out4 = (float4*)(out + (size_t)b * (H * Wd));
#pragma unroll
    for (int i = 0; i < 16; ++i) {
        int g = tid + i * 256;
        int orow = g >> 5;
        int ocol = (g & 31) << 2;
        float4 v = {0.0f, 0.0f, 0.0f, 0.0f};
        int dr = orow - rr;
        if ((unsigned)dr < 16u) {
            float* vp = (float*)&v;
#pragma unroll
            for (int k = 0; k < 4; ++k) {
                int dc = ocol + k - cc;
                if ((unsigned)dc < 16u) vp[k] = sv * wn[dr * 16 + dc];
            }
        }
        out4[g] = v;
    }
}

extern "C" void kernel_launch(void* const* d_in, const int* in_sizes, int n_in,
                              void* d_out, int out_size, void* d_ws, size_t ws_size,
                              hipStream_t stream) {
    const float* in = (const float*)d_in[0];   // (4096,128,128) fp32
    const float* w = (const float*)d_in[1];    // (16,16) fp32
    float* out = (float*)d_out;                // (4096,128,128) fp32
    float* wn = (float*)d_ws;                  // 256 floats scratch

    prep_wn<<<1, 256, 0, stream>>>(w, wn);
    gtpca_main<<<4096, 256, 0, stream>>>(in, wn, out);
}